// Round 4
// baseline (97.874 us; speedup 1.0000x reference)
//
#include <hip/hip_runtime.h>
#include <hip/hip_cooperative_groups.h>

namespace cg = cooperative_groups;

// ROI max-pool. feature_map: (1,256,50,50) f32, bboxes: (512,4) f32,
// out: (512,256,7,7) f32, scale = 1/16, pooled = 7.
//
// ONE cooperative kernel:
//   phase 1: blocks 0..159 transpose NCHW -> NHWC (d_ws), 64x64 LDS tiles
//   grid sync
//   phase 2: block n pools box n (wave-uniform bins, float4 channel loads,
//            permuted LDS staging, coalesced writeback)

#define CC   256
#define HH   50
#define WW   50
#define NBOX 512
#define PP   7
#define SCL  (1.0f / 16.0f)
#define HW   (HH * WW)             // 2500
#define OUT_PER_BOX (CC * PP * PP) // 12544
#define NBIN (PP * PP)             // 49

__global__ __launch_bounds__(512) void fused_roipool_kernel(
    const float* __restrict__ feat,
    const float* __restrict__ boxes,
    float* __restrict__ out,
    float* __restrict__ featT)
{
    __shared__ float smem[OUT_PER_BOX];     // 50176 B, reused across phases
    int bid  = blockIdx.x;
    int tid  = threadIdx.x;
    int lane = tid & 63;

    // ---------------- phase 1: transpose (C,HW) -> (HW,C) ----------------
    if (bid < 160) {                        // 4 c-tiles x 40 hw-tiles
        float (*tile)[65] = (float(*)[65])smem;  // +1 pad
        int tc = bid & 3;
        int th = bid >> 2;
        int c0 = tc * 64, h0 = th * 64;
        int r8 = tid >> 6;                  // 0..7
        for (int it = 0; it < 8; ++it) {
            int r  = r8 + it * 8;
            int hw = h0 + lane;
            if (hw < HW)
                tile[r][lane] = feat[(c0 + r) * HW + hw];   // coalesced
        }
        __syncthreads();
        for (int it = 0; it < 8; ++it) {
            int r  = r8 + it * 8;
            int hw = h0 + r;
            if (hw < HW)
                featT[hw * CC + c0 + lane] = tile[lane][r]; // coalesced, 2-way LDS (free)
        }
    }

    cg::this_grid().sync();                 // featT visible to all blocks

    // ---------------- phase 2: pool box n = bid ---------------------------
    int n    = bid;
    int wave = tid >> 6;

    const float* b = boxes + n * 4;
    int x1 = (int)floorf(b[0] * SCL + 0.5f);
    int y1 = (int)floorf(b[1] * SCL + 0.5f);
    int x2 = (int)floorf(b[2] * SCL + 0.5f);
    int y2 = (int)floorf(b[3] * SCL + 0.5f);
    int rw = max(x2 - x1 + 1, 1);
    int rh = max(y2 - y1 + 1, 1);

    const float* fl = featT + 4 * lane;     // lane's channel quad base

    // staging layout: smem[((c&3)*64 + (c>>2))*49 + pq]
    // store (lane l, sub j, pq) -> (j*64 + l)*49 + pq ; stride 49 (odd) ->
    // bank permutation, 2-way, conflict-free
    for (int pq = wave; pq < NBIN; pq += 8) {
        int p = pq / PP, q = pq % PP;
        int hs = min(max(p * rh / PP + y1, 0), HH);
        int he = min(max(((p + 1) * rh + PP - 1) / PP + y1, 0), HH);
        int ws = min(max(q * rw / PP + x1, 0), WW);
        int we = min(max(((q + 1) * rw + PP - 1) / PP + x1, 0), WW);

        float4 m = make_float4(-INFINITY, -INFINITY, -INFINITY, -INFINITY);
        for (int h = hs; h < he; ++h) {
            const float* base = fl + h * (WW * CC);
            for (int w = ws; w < we; ++w) {
                float4 v = *(const float4*)(base + w * CC);
                m.x = fmaxf(m.x, v.x);
                m.y = fmaxf(m.y, v.y);
                m.z = fmaxf(m.z, v.z);
                m.w = fmaxf(m.w, v.w);
            }
        }
        if ((he <= hs) || (we <= ws))
            m = make_float4(0.0f, 0.0f, 0.0f, 0.0f);

        int base = lane * 49 + pq;
        smem[base           ] = m.x;
        smem[base + 1 * 3136] = m.y;
        smem[base + 2 * 3136] = m.z;
        smem[base + 3 * 3136] = m.w;
    }
    __syncthreads();

    // coalesced writeback of the whole box
    float* on = out + n * OUT_PER_BOX;
    for (int i = tid; i < OUT_PER_BOX; i += 512) {
        int c = i / 49, pq = i % 49;
        on[i] = smem[((c & 3) * 64 + (c >> 2)) * 49 + pq];
    }
}

// ---------- Fallback (round-1 style) if ws too small --------------------
__global__ __launch_bounds__(256) void pool_direct_kernel(
    const float* __restrict__ feat,
    const float* __restrict__ boxes,
    float* __restrict__ out, int total)
{
    int idx = blockIdx.x * blockDim.x + threadIdx.x;
    if (idx >= total) return;
    int q = idx % PP;
    int t = idx / PP;
    int p = t % PP;
    t /= PP;
    int c = t & (CC - 1);
    int n = t >> 8;

    const float* b = boxes + n * 4;
    int x1 = (int)floorf(b[0] * SCL + 0.5f);
    int y1 = (int)floorf(b[1] * SCL + 0.5f);
    int x2 = (int)floorf(b[2] * SCL + 0.5f);
    int y2 = (int)floorf(b[3] * SCL + 0.5f);
    int rw = max(x2 - x1 + 1, 1);
    int rh = max(y2 - y1 + 1, 1);

    int hs = min(max(p * rh / PP + y1, 0), HH);
    int he = min(max(((p + 1) * rh + PP - 1) / PP + y1, 0), HH);
    int ws = min(max(q * rw / PP + x1, 0), WW);
    int we = min(max(((q + 1) * rw + PP - 1) / PP + x1, 0), WW);

    const float* fc = feat + c * HW;
    float m = -INFINITY;
    for (int h = hs; h < he; ++h)
        for (int w = ws; w < we; ++w)
            m = fmaxf(m, fc[h * WW + w]);
    out[idx] = ((he <= hs) || (we <= ws)) ? 0.0f : m;
}

extern "C" void kernel_launch(void* const* d_in, const int* in_sizes, int n_in,
                              void* d_out, int out_size, void* d_ws, size_t ws_size,
                              hipStream_t stream)
{
    const float* feat  = (const float*)d_in[0];
    const float* boxes = (const float*)d_in[1];
    float* out = (float*)d_out;

    const size_t needT = (size_t)HW * CC * sizeof(float);   // 2,560,000 B
    if (ws_size >= needT) {
        float* featT = (float*)d_ws;
        void* args[] = { (void*)&feat, (void*)&boxes, (void*)&out, (void*)&featT };
        hipLaunchCooperativeKernel((const void*)fused_roipool_kernel,
                                   dim3(NBOX), dim3(512), args, 0, stream);
    } else {
        int total = NBOX * CC * PP * PP;
        pool_direct_kernel<<<(total + 255) / 256, 256, 0, stream>>>(
            feat, boxes, out, total);
    }
}

// Round 5
// 22.874 us; speedup vs baseline: 4.2788x; 4.2788x over previous
//
#include <hip/hip_runtime.h>

// ROI max-pool. feature_map: (1,256,50,50) f32, bboxes: (512,4) f32,
// out: (512,256,7,7) f32, scale = 1/16, pooled = 7.
//
// Kernel 1: NCHW -> NHWC transpose into d_ws (channels contiguous).
// Kernel 2: one 1024-thread block per box (16 waves -> 32 waves/CU, 100% occ);
//           wave-uniform bin loops; lane l float4-loads channels 4l..4l+3;
//           LDS staged in FINAL layout (small store conflicts, but writeback
//           is a pure float4 copy, fully coalesced).

#define CC   256
#define HH   50
#define WW   50
#define NBOX 512
#define PP   7
#define SCL  (1.0f / 16.0f)
#define HW   (HH * WW)             // 2500
#define OUT_PER_BOX (CC * PP * PP) // 12544
#define NBIN (PP * PP)             // 49

// ---------- Kernel 1: (C, HW) -> (HW, C) transpose via 64x64 LDS tiles ----
__global__ __launch_bounds__(256) void transpose_kernel(
    const float* __restrict__ feat, float* __restrict__ featT)
{
    __shared__ float tile[64][65];          // +1 pad -> conflict-free column reads
    int tc = blockIdx.x & 3;                // channel tile 0..3
    int th = blockIdx.x >> 2;               // hw tile 0..39
    int c0 = tc * 64, h0 = th * 64;
    int lane = threadIdx.x & 63;
    int row4 = threadIdx.x >> 6;            // 0..3

    for (int it = 0; it < 16; ++it) {
        int r  = row4 + it * 4;             // c-row in tile
        int hw = h0 + lane;
        if (hw < HW)
            tile[r][lane] = feat[(c0 + r) * HW + hw];   // coalesced along hw
    }
    __syncthreads();
    for (int it = 0; it < 16; ++it) {
        int r  = row4 + it * 4;             // hw-row in tile
        int hw = h0 + r;
        if (hw < HW)
            featT[hw * CC + c0 + lane] = tile[lane][r]; // coalesced along c
    }
}

// ---------- Kernel 2: one 1024-thread block per box ----------------------
__global__ __launch_bounds__(1024, 8) void pool_kernel(
    const float* __restrict__ featT,
    const float* __restrict__ boxes,
    float* __restrict__ out)
{
    __shared__ float smem[OUT_PER_BOX];     // 50176 B, FINAL layout: c*49+pq
    int n    = blockIdx.x;
    int tid  = threadIdx.x;
    int wave = tid >> 6;                    // 0..15
    int lane = tid & 63;

    const float* b = boxes + n * 4;
    int x1 = (int)floorf(b[0] * SCL + 0.5f);
    int y1 = (int)floorf(b[1] * SCL + 0.5f);
    int x2 = (int)floorf(b[2] * SCL + 0.5f);
    int y2 = (int)floorf(b[3] * SCL + 0.5f);
    int rw = max(x2 - x1 + 1, 1);
    int rh = max(y2 - y1 + 1, 1);

    const float* fl = featT + 4 * lane;     // lane's channel quad base

    // wave w handles bins pq = w, w+16, w+32 : bounds are wave-uniform
    for (int pq = wave; pq < NBIN; pq += 16) {
        int p = pq / PP, q = pq % PP;
        int hs = min(max(p * rh / PP + y1, 0), HH);
        int he = min(max(((p + 1) * rh + PP - 1) / PP + y1, 0), HH);
        int ws = min(max(q * rw / PP + x1, 0), WW);
        int we = min(max(((q + 1) * rw + PP - 1) / PP + x1, 0), WW);

        float4 m = make_float4(-INFINITY, -INFINITY, -INFINITY, -INFINITY);
        for (int h = hs; h < he; ++h) {
            const float* base = fl + h * (WW * CC);
            for (int w = ws; w < we; ++w) {
                float4 v = *(const float4*)(base + w * CC);  // 1 KB/wave-load
                m.x = fmaxf(m.x, v.x);
                m.y = fmaxf(m.y, v.y);
                m.z = fmaxf(m.z, v.z);
                m.w = fmaxf(m.w, v.w);
            }
        }
        if ((he <= hs) || (we <= ws))
            m = make_float4(0.0f, 0.0f, 0.0f, 0.0f);

        // final layout: smem[(4l+j)*49 + pq]; 8-way conflict on 4 stores/bin
        // (~12 extra cycles per bin) -- traded for a vector writeback below
        int base = (4 * lane) * 49 + pq;
        smem[base      ] = m.x;
        smem[base +  49] = m.y;
        smem[base +  98] = m.z;
        smem[base + 147] = m.w;
    }
    __syncthreads();

    // pure float4 copy: LDS already in output order, fully coalesced stores
    const float4* s4 = (const float4*)smem;
    float4*       o4 = (float4*)(out + n * OUT_PER_BOX);
    for (int i = tid; i < OUT_PER_BOX / 4; i += 1024)   // 3136 float4s
        o4[i] = s4[i];
}

extern "C" void kernel_launch(void* const* d_in, const int* in_sizes, int n_in,
                              void* d_out, int out_size, void* d_ws, size_t ws_size,
                              hipStream_t stream)
{
    const float* feat  = (const float*)d_in[0];
    const float* boxes = (const float*)d_in[1];
    float* out = (float*)d_out;

    float* featT = (float*)d_ws;            // 2,560,000 B needed
    transpose_kernel<<<40 * 4, 256, 0, stream>>>(feat, featT);
    pool_kernel<<<NBOX, 1024, 0, stream>>>(featT, boxes, out);
}